// Round 6
// baseline (398.135 us; speedup 1.0000x reference)
//
#include <hip/hip_runtime.h>
#include <hip/hip_bf16.h>
#include <stdint.h>

typedef unsigned short u16;
typedef __bf16 bf16x8 __attribute__((ext_vector_type(8)));
typedef float f32x4 __attribute__((ext_vector_type(4)));
typedef u16 ushort8 __attribute__((ext_vector_type(8)));
typedef short short4v __attribute__((ext_vector_type(4)));

__device__ __forceinline__ u16 f2bf(float f) {
    unsigned int u = __builtin_bit_cast(unsigned int, f);
    u += 0x7fffu + ((u >> 16) & 1u);
    return (u16)(u >> 16);
}

#define MFMA16(a, b, c) __builtin_amdgcn_mfma_f32_16x16x32_bf16( \
    __builtin_bit_cast(bf16x8, a), __builtin_bit_cast(bf16x8, b), c, 0, 0, 0)

// async global->LDS, 16B per lane. LDS dest = wave-uniform base + lane*16.
__device__ __forceinline__ void async16(void* lds, const void* g) {
    __builtin_amdgcn_global_load_lds(
        (const __attribute__((address_space(1))) unsigned int*)(uintptr_t)g,
        (__attribute__((address_space(3))) unsigned int*)(unsigned int)(uintptr_t)lds,
        16, 0, 0);
}

// ---------------------------------------------------------------------------
// convert fp32 -> bf16, 8 elems/thread
// ---------------------------------------------------------------------------
__global__ __launch_bounds__(256) void convert_bf16(
    const float* __restrict__ src, u16* __restrict__ dst)
{
    int i = blockIdx.x * 256 + threadIdx.x;
    float4 f0 = ((const float4*)src)[i * 2];
    float4 f1 = ((const float4*)src)[i * 2 + 1];
    ushort8 v;
    v[0]=f2bf(f0.x); v[1]=f2bf(f0.y); v[2]=f2bf(f0.z); v[3]=f2bf(f0.w);
    v[4]=f2bf(f1.x); v[5]=f2bf(f1.y); v[6]=f2bf(f1.z); v[7]=f2bf(f1.w);
    ((ushort8*)dst)[i] = v;
}

// ---------------------------------------------------------------------------
// transpose+convert: src fp32 [K][N] -> dst bf16 [N][K]; 64x64 tiles
// ---------------------------------------------------------------------------
__global__ __launch_bounds__(256) void transpose_convert(
    const float* __restrict__ src, u16* __restrict__ dst, int N, int K)
{
    __shared__ u16 T[64][68];
    const int k0 = blockIdx.x * 64, n0 = blockIdx.y * 64;
    const int tid = threadIdx.x;
    const int rr = tid >> 4, cc = (tid & 15) * 4;
    #pragma unroll
    for (int rnd = 0; rnd < 4; ++rnd) {
        int r = rr + rnd * 16;
        float4 f = *(const float4*)&src[(size_t)(k0 + r) * N + n0 + cc];
        u16 v[4] = {f2bf(f.x), f2bf(f.y), f2bf(f.z), f2bf(f.w)};
        *(unsigned long long*)&T[r][cc] = *(unsigned long long*)v;
    }
    __syncthreads();
    #pragma unroll
    for (int rnd = 0; rnd < 4; ++rnd) {
        int rn = rr + rnd * 16;
        u16 v[4];
        #pragma unroll
        for (int j = 0; j < 4; ++j) v[j] = T[cc + j][rn];
        *(unsigned long long*)&dst[(size_t)(n0 + rn) * K + k0 + cc] =
            *(unsigned long long*)v;
    }
}

// ---------------------------------------------------------------------------
// shared 128x128 / BK=64 bf16 GEMM mainloop. A [M][1024], Bt [N][1024].
// LDS layout (swizzled for global_load_lds): [rowblk(16)][chunk(8)][row(8)][8]
// ---------------------------------------------------------------------------
__device__ __forceinline__ void gemm_mainloop(
    const u16* __restrict__ A, const u16* __restrict__ Bt,
    u16* As, u16* Bs, int m0, int n0, int tid, f32x4 acc[4][4])
{
    const int lane = tid & 63, w = tid >> 6;
    const int lr = lane & 15, quad = lane >> 4;
    const int wm = w & 1, wn = w >> 1;
    const int grow = lane & 7, gchunk = lane >> 3;

    for (int k0 = 0; k0 < 1024; k0 += 64) {
        __syncthreads();  // previous iter's frag reads done
        #pragma unroll
        for (int r = 0; r < 4; ++r) {
            int rb = w * 4 + r;
            async16(As + rb * 512,
                    A + (size_t)(m0 + rb * 8 + grow) * 1024 + k0 + gchunk * 8);
            async16(Bs + rb * 512,
                    Bt + (size_t)(n0 + rb * 8 + grow) * 1024 + k0 + gchunk * 8);
        }
        __syncthreads();  // drains vmcnt (async loads done)
        #pragma unroll
        for (int kk = 0; kk < 2; ++kk) {
            ushort8 a[4], b[4];
            #pragma unroll
            for (int mt = 0; mt < 4; ++mt) {
                int rb = wm * 8 + mt * 2 + (lr >> 3);
                a[mt] = *(ushort8*)&As[rb * 512 + (kk * 4 + quad) * 64 + (lr & 7) * 8];
            }
            #pragma unroll
            for (int nt = 0; nt < 4; ++nt) {
                int rb = wn * 8 + nt * 2 + (lr >> 3);
                b[nt] = *(ushort8*)&Bs[rb * 512 + (kk * 4 + quad) * 64 + (lr & 7) * 8];
            }
            #pragma unroll
            for (int mt = 0; mt < 4; ++mt)
                #pragma unroll
                for (int nt = 0; nt < 4; ++nt)
                    acc[mt][nt] = MFMA16(a[mt], b[nt], acc[mt][nt]);
        }
    }
}

// ---------------------------------------------------------------------------
// Kernel: qkv = xb @ WqkvT^T + bqkv
// q,k stored [b,h,t,64]; v stored TRANSPOSED [b,h,64,t]
// ---------------------------------------------------------------------------
__global__ __launch_bounds__(256) void qkv_gemm(
    const u16* __restrict__ xb, const u16* __restrict__ Wt,
    const float* __restrict__ bias, u16* __restrict__ qkvb)
{
    __shared__ u16 As[8192], Bs[8192];
    const int m0 = blockIdx.x * 128, n0 = blockIdx.y * 128;
    const int tid = threadIdx.x;
    f32x4 acc[4][4] = {};
    gemm_mainloop(xb, Wt, As, Bs, m0, n0, tid, acc);

    const int lane = tid & 63, w = tid >> 6;
    const int lr = lane & 15, quad = lane >> 4;
    const int wm = w & 1, wn = w >> 1;
    const int which = n0 >> 10;  // uniform per block (128 | 1024)
    float bv[4];
    #pragma unroll
    for (int nt = 0; nt < 4; ++nt) bv[nt] = bias[n0 + wn * 64 + nt * 16 + lr];

    if (which == 2) {
        // V: transposed store [b,h,d,t], 4 regs = 4 consecutive t -> b64
        u16* vT = qkvb + (size_t)2 * 8388608;
        #pragma unroll
        for (int nt = 0; nt < 4; ++nt) {
            int n = n0 + wn * 64 + nt * 16 + lr;
            int hh = (n >> 6) & 15, d = n & 63;
            #pragma unroll
            for (int mt = 0; mt < 4; ++mt) {
                int mbase = m0 + wm * 64 + mt * 16 + quad * 4;
                int b_idx = mbase >> 11, t0 = mbase & 2047;
                short4v o4;
                #pragma unroll
                for (int reg = 0; reg < 4; ++reg)
                    o4[reg] = (short)f2bf(acc[mt][nt][reg] + bv[nt]);
                *(short4v*)&vT[((size_t)(b_idx * 16 + hh) * 64 + d) * 2048 + t0] = o4;
            }
        }
    } else {
        u16* dst = qkvb + (size_t)which * 8388608;
        #pragma unroll
        for (int mt = 0; mt < 4; ++mt)
          #pragma unroll
          for (int nt = 0; nt < 4; ++nt) {
            int n = n0 + wn * 64 + nt * 16 + lr;
            int hh = (n >> 6) & 15, d = n & 63;
            #pragma unroll
            for (int reg = 0; reg < 4; ++reg) {
                int m = m0 + wm * 64 + mt * 16 + quad * 4 + reg;
                int b_idx = m >> 11, t_idx = m & 2047;
                dst[(((size_t)(b_idx * 16 + hh) * 2048 + t_idx) << 6) + d] =
                    f2bf(acc[mt][nt][reg] + bv[nt]);
            }
          }
    }
}

// ---------------------------------------------------------------------------
// Kernel: out = attn_o @ WoutT^T + bout (fp32 out)
// ---------------------------------------------------------------------------
__global__ __launch_bounds__(256) void out_gemm(
    const u16* __restrict__ A, const u16* __restrict__ Wt,
    const float* __restrict__ bias, float* __restrict__ out)
{
    __shared__ u16 As[8192], Bs[8192];
    const int m0 = blockIdx.x * 128, n0 = blockIdx.y * 128;
    const int tid = threadIdx.x;
    f32x4 acc[4][4] = {};
    gemm_mainloop(A, Wt, As, Bs, m0, n0, tid, acc);

    const int lane = tid & 63, w = tid >> 6;
    const int lr = lane & 15, quad = lane >> 4;
    const int wm = w & 1, wn = w >> 1;
    float bv[4];
    #pragma unroll
    for (int nt = 0; nt < 4; ++nt) bv[nt] = bias[n0 + wn * 64 + nt * 16 + lr];
    #pragma unroll
    for (int mt = 0; mt < 4; ++mt)
      #pragma unroll
      for (int nt = 0; nt < 4; ++nt)
        #pragma unroll
        for (int reg = 0; reg < 4; ++reg) {
            int m = m0 + wm * 64 + mt * 16 + quad * 4 + reg;
            int n = n0 + wn * 64 + nt * 16 + lr;
            out[(size_t)m * 1024 + n] = acc[mt][nt][reg] + bv[nt];
        }
}

// ---------------------------------------------------------------------------
// Flash attention — R2-PROVEN STRUCTURE (isolation round).
// Grid (16 pairs, 16 h, 4 b); block 256 = 4 waves; q-tiles {p, 31-p}.
// S = Q.K^T (A=Qs rows, B=Ks rows); 16-lane shuffle softmax (__expf);
// P -> Ps[64][72] round trip; PV with B = Vts[d][t] rows, where Vts is
// staged DIRECTLY from the pre-transposed global V^T (no in-kernel
// transpose). 3 barriers/iter, single-buffered — exactly R2's schedule.
// ---------------------------------------------------------------------------
__global__ __launch_bounds__(256) void attn_kernel(
    const u16* __restrict__ qkvb, u16* __restrict__ o_ws)
{
    const int p = blockIdx.x, h = blockIdx.y, b = blockIdx.z;
    const size_t bh = (size_t)(b * 16 + h) * 131072;
    const u16* Qb = qkvb + bh;
    const u16* Kb = qkvb + 8388608 + bh;
    const u16* Vt = qkvb + 2 * 8388608 + bh;   // [64][2048]
    __shared__ u16 Qs[64 * 72];
    __shared__ u16 Ks[64 * 72];
    __shared__ u16 Vts[64 * 72];  // [d][t]
    __shared__ u16 Ps[64 * 72];
    const int tid = threadIdx.x, lane = tid & 63, w = tid >> 6;
    const int lr = lane & 15, quad = lane >> 4;
    const int sr = tid >> 2, sc = (tid & 3) * 16;
    const float scale = 0.125f;

    for (int pass = 0; pass < 2; ++pass) {
        const int qt = pass ? (31 - p) : p;
        __syncthreads();  // prev pass's reads of Qs done
        {
            const u16* src = Qb + (size_t)(qt * 64 + sr) * 64 + sc;
            *(uint4*)&Qs[sr * 72 + sc]     = *(const uint4*)src;
            *(uint4*)&Qs[sr * 72 + sc + 8] = *(const uint4*)(src + 8);
        }
        f32x4 o_acc[4] = {};
        float m_i[4], l_i[4];
        #pragma unroll
        for (int r = 0; r < 4; ++r) { m_i[r] = -1e30f; l_i[r] = 0.f; }

        for (int kt = 0; kt <= qt; ++kt) {
            __syncthreads();  // prev iter's reads of Ks/Vts/Ps done (Qs staged)
            {
                const u16* ksrc = Kb + (size_t)(kt * 64 + sr) * 64 + sc;
                *(uint4*)&Ks[sr * 72 + sc]     = *(const uint4*)ksrc;
                *(uint4*)&Ks[sr * 72 + sc + 8] = *(const uint4*)(ksrc + 8);
                const u16* vsrc = Vt + (size_t)sr * 2048 + kt * 64 + sc;
                *(uint4*)&Vts[sr * 72 + sc]     = *(const uint4*)vsrc;
                *(uint4*)&Vts[sr * 72 + sc + 8] = *(const uint4*)(vsrc + 8);
            }
            __syncthreads();

            // S = Q K^T (wave w owns q-rows [16w, 16w+16))
            f32x4 s[4] = {};
            #pragma unroll
            for (int nt = 0; nt < 4; ++nt)
                #pragma unroll
                for (int kk = 0; kk < 2; ++kk) {
                    ushort8 a  = *(ushort8*)&Qs[(w * 16 + lr) * 72 + kk * 32 + quad * 8];
                    ushort8 bb = *(ushort8*)&Ks[(nt * 16 + lr) * 72 + kk * 32 + quad * 8];
                    s[nt] = MFMA16(a, bb, s[nt]);
                }
            // scale + causal mask (diagonal tile only)
            if (kt == qt) {
                #pragma unroll
                for (int nt = 0; nt < 4; ++nt)
                    #pragma unroll
                    for (int reg = 0; reg < 4; ++reg) {
                        int qr = w * 16 + quad * 4 + reg;
                        int kc = nt * 16 + lr;
                        s[nt][reg] = (kc > qr) ? -1e30f : s[nt][reg] * scale;
                    }
            } else {
                #pragma unroll
                for (int nt = 0; nt < 4; ++nt)
                    #pragma unroll
                    for (int reg = 0; reg < 4; ++reg) s[nt][reg] *= scale;
            }
            // online softmax; row = 16w + quad*4 + reg, cols across 16 lanes
            float pr[4][4], alpha[4];
            #pragma unroll
            for (int reg = 0; reg < 4; ++reg) {
                float mx = fmaxf(fmaxf(s[0][reg], s[1][reg]),
                                 fmaxf(s[2][reg], s[3][reg]));
                #pragma unroll
                for (int off = 1; off < 16; off <<= 1)
                    mx = fmaxf(mx, __shfl_xor(mx, off, 64));
                float mnew = fmaxf(m_i[reg], mx);
                alpha[reg] = __expf(m_i[reg] - mnew);
                m_i[reg] = mnew;
                float rs = 0.f;
                #pragma unroll
                for (int nt = 0; nt < 4; ++nt) {
                    float pv = __expf(s[nt][reg] - mnew);
                    pr[nt][reg] = pv;
                    rs += pv;
                }
                #pragma unroll
                for (int off = 1; off < 16; off <<= 1)
                    rs += __shfl_xor(rs, off, 64);
                l_i[reg] = l_i[reg] * alpha[reg] + rs;
            }
            #pragma unroll
            for (int dt = 0; dt < 4; ++dt)
                #pragma unroll
                for (int reg = 0; reg < 4; ++reg) o_acc[dt][reg] *= alpha[reg];
            // P -> LDS (C-layout coords only)
            #pragma unroll
            for (int nt = 0; nt < 4; ++nt)
                #pragma unroll
                for (int reg = 0; reg < 4; ++reg)
                    Ps[(w * 16 + quad * 4 + reg) * 72 + nt * 16 + lr] =
                        f2bf(pr[nt][reg]);
            __syncthreads();  // Ps visible
            // O += P V  (B = V^T rows: same contiguous-k convention as A)
            #pragma unroll
            for (int kk = 0; kk < 2; ++kk) {
                ushort8 pa = *(ushort8*)&Ps[(w * 16 + lr) * 72 + kk * 32 + quad * 8];
                #pragma unroll
                for (int dt = 0; dt < 4; ++dt) {
                    ushort8 vb = *(ushort8*)&Vts[(dt * 16 + lr) * 72 + kk * 32 + quad * 8];
                    o_acc[dt] = MFMA16(pa, vb, o_acc[dt]);
                }
            }
        }

        // epilogue: normalize, write bf16 [b, t, h*64 + d]
        #pragma unroll
        for (int dt = 0; dt < 4; ++dt)
            #pragma unroll
            for (int reg = 0; reg < 4; ++reg) {
                int row = w * 16 + quad * 4 + reg;
                int tq = qt * 64 + row;
                float ov = o_acc[dt][reg] / l_i[reg];
                o_ws[((size_t)(b * 2048 + tq) << 10) + h * 64 + dt * 16 + lr] =
                    f2bf(ov);
            }
    }
}

extern "C" void kernel_launch(void* const* d_in, const int* in_sizes, int n_in,
                              void* d_out, int out_size, void* d_ws, size_t ws_size,
                              hipStream_t stream)
{
    const float* x    = (const float*)d_in[0];
    const float* Wqkv = (const float*)d_in[1];
    const float* bqkv = (const float*)d_in[2];
    const float* Wout = (const float*)d_in[3];
    const float* bout = (const float*)d_in[4];
    float* out = (float*)d_out;

    u16* qkvb = (u16*)d_ws;                    // q | k | vT, 3 * 8388608 elems
    u16* xb   = qkvb + (size_t)3 * 8388608;    // 8388608 elems; reused as attn_o
    u16* wT   = qkvb + (size_t)4 * 8388608;    // up to 3072*1024 elems
    u16* attn_o = xb;

    convert_bf16<<<4096, 256, 0, stream>>>(x, xb);
    transpose_convert<<<dim3(16, 48), 256, 0, stream>>>(Wqkv, wT, 3072, 1024);
    qkv_gemm<<<dim3(64, 24), 256, 0, stream>>>(xb, wT, bqkv, qkvb);
    attn_kernel<<<dim3(16, 16, 4), 256, 0, stream>>>(qkvb, attn_o);
    transpose_convert<<<dim3(16, 16), 256, 0, stream>>>(Wout, wT, 1024, 1024);
    out_gemm<<<dim3(64, 8), 256, 0, stream>>>(attn_o, wT, bout, out);
}

// Round 7
// 333.252 us; speedup vs baseline: 1.1947x; 1.1947x over previous
//
#include <hip/hip_runtime.h>
#include <hip/hip_bf16.h>
#include <stdint.h>

typedef unsigned short u16;
typedef __bf16 bf16x8 __attribute__((ext_vector_type(8)));
typedef float f32x4 __attribute__((ext_vector_type(4)));
typedef u16 ushort8 __attribute__((ext_vector_type(8)));
typedef short short4v __attribute__((ext_vector_type(4)));

__device__ __forceinline__ u16 f2bf(float f) {
    unsigned int u = __builtin_bit_cast(unsigned int, f);
    u += 0x7fffu + ((u >> 16) & 1u);
    return (u16)(u >> 16);
}

#define MFMA16(a, b, c) __builtin_amdgcn_mfma_f32_16x16x32_bf16( \
    __builtin_bit_cast(bf16x8, a), __builtin_bit_cast(bf16x8, b), c, 0, 0, 0)

#if defined(__has_builtin)
#if __has_builtin(__builtin_amdgcn_exp2f)
#define EXP2(x) __builtin_amdgcn_exp2f(x)
#endif
#endif
#ifndef EXP2
#define EXP2(x) __expf((x) * 0.69314718f)
#endif

// async global->LDS, 16B per lane. LDS dest = wave-uniform base + lane*16.
__device__ __forceinline__ void async16(void* lds, const void* g) {
    __builtin_amdgcn_global_load_lds(
        (const __attribute__((address_space(1))) unsigned int*)(uintptr_t)g,
        (__attribute__((address_space(3))) unsigned int*)(unsigned int)(uintptr_t)lds,
        16, 0, 0);
}

// ---------------------------------------------------------------------------
// convert fp32 -> bf16, 8 elems/thread
// ---------------------------------------------------------------------------
__global__ __launch_bounds__(256) void convert_bf16(
    const float* __restrict__ src, u16* __restrict__ dst)
{
    int i = blockIdx.x * 256 + threadIdx.x;
    float4 f0 = ((const float4*)src)[i * 2];
    float4 f1 = ((const float4*)src)[i * 2 + 1];
    ushort8 v;
    v[0]=f2bf(f0.x); v[1]=f2bf(f0.y); v[2]=f2bf(f0.z); v[3]=f2bf(f0.w);
    v[4]=f2bf(f1.x); v[5]=f2bf(f1.y); v[6]=f2bf(f1.z); v[7]=f2bf(f1.w);
    ((ushort8*)dst)[i] = v;
}

// ---------------------------------------------------------------------------
// transpose+convert: src fp32 [K][N] -> dst bf16 [N][K]; 64x64 tiles
// ---------------------------------------------------------------------------
__global__ __launch_bounds__(256) void transpose_convert(
    const float* __restrict__ src, u16* __restrict__ dst, int N, int K)
{
    __shared__ u16 T[64][68];
    const int k0 = blockIdx.x * 64, n0 = blockIdx.y * 64;
    const int tid = threadIdx.x;
    const int rr = tid >> 4, cc = (tid & 15) * 4;
    #pragma unroll
    for (int rnd = 0; rnd < 4; ++rnd) {
        int r = rr + rnd * 16;
        float4 f = *(const float4*)&src[(size_t)(k0 + r) * N + n0 + cc];
        u16 v[4] = {f2bf(f.x), f2bf(f.y), f2bf(f.z), f2bf(f.w)};
        *(unsigned long long*)&T[r][cc] = *(unsigned long long*)v;
    }
    __syncthreads();
    #pragma unroll
    for (int rnd = 0; rnd < 4; ++rnd) {
        int rn = rr + rnd * 16;
        u16 v[4];
        #pragma unroll
        for (int j = 0; j < 4; ++j) v[j] = T[cc + j][rn];
        *(unsigned long long*)&dst[(size_t)(n0 + rn) * K + k0 + cc] =
            *(unsigned long long*)v;
    }
}

// ---------------------------------------------------------------------------
// shared 128x128 / BK=64 bf16 GEMM mainloop. A [M][1024], Bt [N][1024].
// LDS layout (swizzled for global_load_lds): [rowblk(16)][chunk(8)][row(8)][8]
// ---------------------------------------------------------------------------
__device__ __forceinline__ void gemm_mainloop(
    const u16* __restrict__ A, const u16* __restrict__ Bt,
    u16* As, u16* Bs, int m0, int n0, int tid, f32x4 acc[4][4])
{
    const int lane = tid & 63, w = tid >> 6;
    const int lr = lane & 15, quad = lane >> 4;
    const int wm = w & 1, wn = w >> 1;
    const int grow = lane & 7, gchunk = lane >> 3;

    for (int k0 = 0; k0 < 1024; k0 += 64) {
        __syncthreads();  // previous iter's frag reads done
        #pragma unroll
        for (int r = 0; r < 4; ++r) {
            int rb = w * 4 + r;
            async16(As + rb * 512,
                    A + (size_t)(m0 + rb * 8 + grow) * 1024 + k0 + gchunk * 8);
            async16(Bs + rb * 512,
                    Bt + (size_t)(n0 + rb * 8 + grow) * 1024 + k0 + gchunk * 8);
        }
        __syncthreads();  // drains vmcnt (async loads done)
        #pragma unroll
        for (int kk = 0; kk < 2; ++kk) {
            ushort8 a[4], b[4];
            #pragma unroll
            for (int mt = 0; mt < 4; ++mt) {
                int rb = wm * 8 + mt * 2 + (lr >> 3);
                a[mt] = *(ushort8*)&As[rb * 512 + (kk * 4 + quad) * 64 + (lr & 7) * 8];
            }
            #pragma unroll
            for (int nt = 0; nt < 4; ++nt) {
                int rb = wn * 8 + nt * 2 + (lr >> 3);
                b[nt] = *(ushort8*)&Bs[rb * 512 + (kk * 4 + quad) * 64 + (lr & 7) * 8];
            }
            #pragma unroll
            for (int mt = 0; mt < 4; ++mt)
                #pragma unroll
                for (int nt = 0; nt < 4; ++nt)
                    acc[mt][nt] = MFMA16(a[mt], b[nt], acc[mt][nt]);
        }
    }
}

// ---------------------------------------------------------------------------
// Kernel: qkv = xb @ WqkvT^T + bqkv
// q,k stored [b,h,t,64]; v stored TRANSPOSED [b,h,64,t]
// ---------------------------------------------------------------------------
__global__ __launch_bounds__(256) void qkv_gemm(
    const u16* __restrict__ xb, const u16* __restrict__ Wt,
    const float* __restrict__ bias, u16* __restrict__ qkvb)
{
    __shared__ u16 As[8192], Bs[8192];
    const int m0 = blockIdx.x * 128, n0 = blockIdx.y * 128;
    const int tid = threadIdx.x;
    f32x4 acc[4][4] = {};
    gemm_mainloop(xb, Wt, As, Bs, m0, n0, tid, acc);

    const int lane = tid & 63, w = tid >> 6;
    const int lr = lane & 15, quad = lane >> 4;
    const int wm = w & 1, wn = w >> 1;
    const int which = n0 >> 10;  // uniform per block (128 | 1024)
    float bv[4];
    #pragma unroll
    for (int nt = 0; nt < 4; ++nt) bv[nt] = bias[n0 + wn * 64 + nt * 16 + lr];

    if (which == 2) {
        // V: transposed store [b,h,d,t], 4 regs = 4 consecutive t -> b64
        u16* vT = qkvb + (size_t)2 * 8388608;
        #pragma unroll
        for (int nt = 0; nt < 4; ++nt) {
            int n = n0 + wn * 64 + nt * 16 + lr;
            int hh = (n >> 6) & 15, d = n & 63;
            #pragma unroll
            for (int mt = 0; mt < 4; ++mt) {
                int mbase = m0 + wm * 64 + mt * 16 + quad * 4;
                int b_idx = mbase >> 11, t0 = mbase & 2047;
                short4v o4;
                #pragma unroll
                for (int reg = 0; reg < 4; ++reg)
                    o4[reg] = (short)f2bf(acc[mt][nt][reg] + bv[nt]);
                *(short4v*)&vT[((size_t)(b_idx * 16 + hh) * 64 + d) * 2048 + t0] = o4;
            }
        }
    } else {
        u16* dst = qkvb + (size_t)which * 8388608;
        #pragma unroll
        for (int mt = 0; mt < 4; ++mt)
          #pragma unroll
          for (int nt = 0; nt < 4; ++nt) {
            int n = n0 + wn * 64 + nt * 16 + lr;
            int hh = (n >> 6) & 15, d = n & 63;
            #pragma unroll
            for (int reg = 0; reg < 4; ++reg) {
                int m = m0 + wm * 64 + mt * 16 + quad * 4 + reg;
                int b_idx = m >> 11, t_idx = m & 2047;
                dst[(((size_t)(b_idx * 16 + hh) * 2048 + t_idx) << 6) + d] =
                    f2bf(acc[mt][nt][reg] + bv[nt]);
            }
          }
    }
}

// ---------------------------------------------------------------------------
// Kernel: out = attn_o @ WoutT^T + bout (fp32 out)
// ---------------------------------------------------------------------------
__global__ __launch_bounds__(256) void out_gemm(
    const u16* __restrict__ A, const u16* __restrict__ Wt,
    const float* __restrict__ bias, float* __restrict__ out)
{
    __shared__ u16 As[8192], Bs[8192];
    const int m0 = blockIdx.x * 128, n0 = blockIdx.y * 128;
    const int tid = threadIdx.x;
    f32x4 acc[4][4] = {};
    gemm_mainloop(A, Wt, As, Bs, m0, n0, tid, acc);

    const int lane = tid & 63, w = tid >> 6;
    const int lr = lane & 15, quad = lane >> 4;
    const int wm = w & 1, wn = w >> 1;
    float bv[4];
    #pragma unroll
    for (int nt = 0; nt < 4; ++nt) bv[nt] = bias[n0 + wn * 64 + nt * 16 + lr];
    #pragma unroll
    for (int mt = 0; mt < 4; ++mt)
      #pragma unroll
      for (int nt = 0; nt < 4; ++nt)
        #pragma unroll
        for (int reg = 0; reg < 4; ++reg) {
            int m = m0 + wm * 64 + mt * 16 + quad * 4 + reg;
            int n = n0 + wn * 64 + nt * 16 + lr;
            out[(size_t)m * 1024 + n] = acc[mt][nt][reg] + bv[nt];
        }
}

// ---------------------------------------------------------------------------
// Flash attention — R6-proven structure, de-latencied.
// Grid (16 pairs, 16 h, 4 b); block 256 = 4 waves; q-tiles {p, 31-p}.
// Deltas vs R6 (each mechanical / GEMM-proven):
//  - Q A-frags in registers from global (same contiguous-k convention)
//  - K double-buffered + V single-buffered via global_load_lds with the
//    GEMM-proven swizzle [rb(8)][chunk(8)][row(8)][8]; 2 barriers/iter
//  - softmax in exp2 domain (scale*log2e folded into existing multiply)
// QK math, mask, shuffle softmax, Ps round-trip, PV, epilogue: unchanged.
// ---------------------------------------------------------------------------
__global__ __launch_bounds__(256) void attn_kernel(
    const u16* __restrict__ qkvb, u16* __restrict__ o_ws)
{
    const int p = blockIdx.x, h = blockIdx.y, b = blockIdx.z;
    const size_t bh = (size_t)(b * 16 + h) * 131072;
    const u16* Qb = qkvb + bh;
    const u16* Kb = qkvb + 8388608 + bh;
    const u16* Vt = qkvb + 2 * 8388608 + bh;   // [64][2048]
    __shared__ u16 Ks[2][4096];   // [rb(8)][chunk(8)][row(8)][8]
    __shared__ u16 Vts[4096];     // same swizzle, rows = d
    __shared__ u16 Ps[64 * 72];
    const int tid = threadIdx.x, lane = tid & 63, w = tid >> 6;
    const int lr = lane & 15, quad = lane >> 4;
    const int grow = lane & 7, gchunk = lane >> 3;
    const float kscale = 0.125f * 1.44269504f;  // scale * log2(e)

    for (int pass = 0; pass < 2; ++pass) {
        const int qt = pass ? (31 - p) : p;
        // Q A-fragments straight from global (contiguous k-chunks)
        ushort8 qf[2];
        {
            const u16* qr = Qb + (size_t)(qt * 64 + w * 16 + lr) * 64 + quad * 8;
            qf[0] = *(const ushort8*)qr;
            qf[1] = *(const ushort8*)(qr + 32);
        }
        f32x4 o_acc[4] = {};
        float m_i[4], l_i[4];
        #pragma unroll
        for (int r = 0; r < 4; ++r) { m_i[r] = -1e30f; l_i[r] = 0.f; }

        __syncthreads();  // prev pass's LDS reads done
        #pragma unroll
        for (int r = 0; r < 2; ++r) {   // stage K(0)
            int rb = w * 2 + r;
            async16(&Ks[0][rb * 512], Kb + (size_t)(rb * 8 + grow) * 64 + gchunk * 8);
        }

        for (int kt = 0; kt <= qt; ++kt) {
            const int buf = kt & 1;
            __syncthreads();  // barrier A: K(kt) staged; prev iter's PV reads done

            // prefetch K(kt+1) into other buffer; stage V(kt) just-in-time
            #pragma unroll
            for (int r = 0; r < 2; ++r) {
                int rb = w * 2 + r;
                if (kt < qt)
                    async16(&Ks[buf ^ 1][rb * 512],
                            Kb + (size_t)((kt + 1) * 64 + rb * 8 + grow) * 64 + gchunk * 8);
                async16(&Vts[rb * 512],
                        Vt + (size_t)(rb * 8 + grow) * 2048 + kt * 64 + gchunk * 8);
            }

            // S = Q K^T (wave w owns q-rows [16w, 16w+16))
            f32x4 s[4] = {};
            #pragma unroll
            for (int nt = 0; nt < 4; ++nt)
                #pragma unroll
                for (int kk = 0; kk < 2; ++kk) {
                    ushort8 bb = *(ushort8*)&Ks[buf][(nt * 2 + (lr >> 3)) * 512 +
                                                     (kk * 4 + quad) * 64 + (lr & 7) * 8];
                    s[nt] = MFMA16(qf[kk], bb, s[nt]);
                }
            // scale (exp2 domain) + causal mask (diagonal tile only)
            if (kt == qt) {
                #pragma unroll
                for (int nt = 0; nt < 4; ++nt)
                    #pragma unroll
                    for (int reg = 0; reg < 4; ++reg) {
                        int qr = w * 16 + quad * 4 + reg;
                        int kc = nt * 16 + lr;
                        s[nt][reg] = (kc > qr) ? -1e30f : s[nt][reg] * kscale;
                    }
            } else {
                #pragma unroll
                for (int nt = 0; nt < 4; ++nt)
                    #pragma unroll
                    for (int reg = 0; reg < 4; ++reg) s[nt][reg] *= kscale;
            }
            // online softmax (base-2); row = 16w + quad*4 + reg, cols across 16 lanes
            float pr[4][4], alpha[4];
            #pragma unroll
            for (int reg = 0; reg < 4; ++reg) {
                float mx = fmaxf(fmaxf(s[0][reg], s[1][reg]),
                                 fmaxf(s[2][reg], s[3][reg]));
                #pragma unroll
                for (int off = 1; off < 16; off <<= 1)
                    mx = fmaxf(mx, __shfl_xor(mx, off, 64));
                float mnew = fmaxf(m_i[reg], mx);
                alpha[reg] = EXP2(m_i[reg] - mnew);
                m_i[reg] = mnew;
                float rs = 0.f;
                #pragma unroll
                for (int nt = 0; nt < 4; ++nt) {
                    float pv = EXP2(s[nt][reg] - mnew);
                    pr[nt][reg] = pv;
                    rs += pv;
                }
                #pragma unroll
                for (int off = 1; off < 16; off <<= 1)
                    rs += __shfl_xor(rs, off, 64);
                l_i[reg] = l_i[reg] * alpha[reg] + rs;
            }
            #pragma unroll
            for (int dt = 0; dt < 4; ++dt)
                #pragma unroll
                for (int reg = 0; reg < 4; ++reg) o_acc[dt][reg] *= alpha[reg];
            // P -> LDS (C-layout coords only)
            #pragma unroll
            for (int nt = 0; nt < 4; ++nt)
                #pragma unroll
                for (int reg = 0; reg < 4; ++reg)
                    Ps[(w * 16 + quad * 4 + reg) * 72 + nt * 16 + lr] =
                        f2bf(pr[nt][reg]);

            __syncthreads();  // barrier B: Ps visible; V(kt) drained (vmcnt)

            // O += P V  (A = Ps rows, B = V^T rows; contiguous-k both sides)
            #pragma unroll
            for (int kk = 0; kk < 2; ++kk) {
                ushort8 pa = *(ushort8*)&Ps[(w * 16 + lr) * 72 + kk * 32 + quad * 8];
                #pragma unroll
                for (int dt = 0; dt < 4; ++dt) {
                    ushort8 vb = *(ushort8*)&Vts[(dt * 2 + (lr >> 3)) * 512 +
                                                 (kk * 4 + quad) * 64 + (lr & 7) * 8];
                    o_acc[dt] = MFMA16(pa, vb, o_acc[dt]);
                }
            }
        }

        // epilogue: normalize, write bf16 [b, t, h*64 + d]
        float rl[4];
        #pragma unroll
        for (int reg = 0; reg < 4; ++reg) rl[reg] = 1.0f / l_i[reg];
        #pragma unroll
        for (int dt = 0; dt < 4; ++dt)
            #pragma unroll
            for (int reg = 0; reg < 4; ++reg) {
                int row = w * 16 + quad * 4 + reg;
                int tq = qt * 64 + row;
                o_ws[((size_t)(b * 2048 + tq) << 10) + h * 64 + dt * 16 + lr] =
                    f2bf(o_acc[dt][reg] * rl[reg]);
            }
    }
}

extern "C" void kernel_launch(void* const* d_in, const int* in_sizes, int n_in,
                              void* d_out, int out_size, void* d_ws, size_t ws_size,
                              hipStream_t stream)
{
    const float* x    = (const float*)d_in[0];
    const float* Wqkv = (const float*)d_in[1];
    const float* bqkv = (const float*)d_in[2];
    const float* Wout = (const float*)d_in[3];
    const float* bout = (const float*)d_in[4];
    float* out = (float*)d_out;

    u16* qkvb = (u16*)d_ws;                    // q | k | vT, 3 * 8388608 elems
    u16* xb   = qkvb + (size_t)3 * 8388608;    // 8388608 elems; reused as attn_o
    u16* wT   = qkvb + (size_t)4 * 8388608;    // up to 3072*1024 elems
    u16* attn_o = xb;

    convert_bf16<<<4096, 256, 0, stream>>>(x, xb);
    transpose_convert<<<dim3(16, 48), 256, 0, stream>>>(Wqkv, wT, 3072, 1024);
    qkv_gemm<<<dim3(64, 24), 256, 0, stream>>>(xb, wT, bqkv, qkvb);
    attn_kernel<<<dim3(16, 16, 4), 256, 0, stream>>>(qkvb, attn_o);
    transpose_convert<<<dim3(16, 16), 256, 0, stream>>>(Wout, wT, 1024, 1024);
    out_gemm<<<dim3(64, 8), 256, 0, stream>>>(attn_o, wT, bout, out);
}